// Round 5
// baseline (245.021 us; speedup 1.0000x reference)
//
#include <hip/hip_runtime.h>

// KGL: per-patch kernel generation.
//  x: (8, 768, 768, 9) fp32. PSZ=24 -> p1=p2=32, N=1024, N*B=8192 patches.
//  Patch flat index j = b*1024 + pi*32 + pj (raw-reshape preserves buffer order).
//  out[0 .. 663551]        = wg1: conv3x3 stride8 (pad=0 -> 3x3) clipped per-oc over spatial
//  out[663552 .. 1327103]  = wg2: (GAP @ dense_w + b) as 9x9, clipped per-column over rows
//
// R5: single-pass HBM. All 4 waves stream 6 patch rows each (GAP colsums);
// the 9 conv-relevant rows (row%8 < 3) are tee'd into LDS during the stream.
// Conv reads ONLY LDS (ds_read_b128, 9-lane broadcast groups) -> no global
// re-reads, fetch == mandatory 170 MB. ~15 KB LDS, 8 blocks/CU.

#define PSZ 24
#define NCH 9
#define HW 768
#define NPIX (PSZ*PSZ)              // 576
#define ROWF (PSZ*NCH)              // 216 floats per patch row
#define ROWV4 54                    // float4s per patch row
#define XROWF (HW*NCH)              // 6912 floats per image row
#define OUT2_OFF 663552

__global__ __launch_bounds__(256) void kgl_kernel(
    const float* __restrict__ x,
    const float* __restrict__ conv_w,   // (3,3,9,9) HWIO flat, 729
    const float* __restrict__ conv_b,   // (9,)
    const float* __restrict__ dense_w,  // (9,81)
    const float* __restrict__ dense_b,  // (81,)
    float* __restrict__ out)
{
    __shared__ __align__(16) float convrows[9*ROWF]; // rows 0,1,2,8,9,10,16,17,18
    __shared__ __align__(16) float cw[732];          // 729 used
    __shared__ __align__(16) float colP[4*ROWF];     // per-wave column sums
    __shared__ float gap_s[NCH];
    __shared__ float co_s[81];
    __shared__ float d_s[81];

    const int j    = blockIdx.x;
    const int b    = j >> 10;
    const int rem  = j & 1023;
    const int pi   = rem >> 5;
    const int pj   = rem & 31;
    const int tid  = threadIdx.x;
    const int w    = tid >> 6;
    const int lane = tid & 63;

    const size_t base = ((size_t)(b*HW + pi*PSZ) * HW + (size_t)pj*PSZ) * NCH;
    const float* gbase = x + base;

    // ---- Phase A: wave0 stages conv_w; all waves stream 6 rows each ----
    if (w == 0) {
        #pragma unroll
        for (int i = 0; i < 3; ++i) {
            int e = lane + i*64;
            if (e < 182)
                reinterpret_cast<float4*>(cw)[e] =
                    reinterpret_cast<const float4*>(conv_w)[e];
        }
        if (lane == 0) cw[728] = conv_w[728];
    }
    if (lane < ROWV4) {
        float4 acc = make_float4(0.f, 0.f, 0.f, 0.f);
        #pragma unroll
        for (int r6 = 0; r6 < 6; ++r6) {
            const int row = w*6 + r6;
            float4 v = *reinterpret_cast<const float4*>(
                gbase + (size_t)row*XROWF + (size_t)lane*4);
            acc.x += v.x; acc.y += v.y; acc.z += v.z; acc.w += v.w;
            if ((row & 7) < 3) {   // conv-relevant row (wave-uniform branch)
                const int ci = (row & 7) + 3*(row >> 3);
                reinterpret_cast<float4*>(convrows)[ci*ROWV4 + lane] = v;
            }
        }
        reinterpret_cast<float4*>(colP)[w*ROWV4 + lane] = acc;
    }
    __syncthreads();  // convrows, colP, cw valid

    // ---- Phase B: conv from LDS (tid<81); GAP fold (tid 128..136) ----
    float conv_acc = 0.f;
    if (tid < 81) {
        const int oy = tid / 27;
        const int ox = (tid / 9) % 3;
        const int oc = tid % 9;
        float acc = conv_b[oc];
        #pragma unroll
        for (int ky = 0; ky < 3; ++ky) {
            // 27 needed floats, read 7 aligned float4 (28) from LDS
            const float* rp = &convrows[(3*oy + ky)*ROWF + ox*72];
            float pv[28];
            #pragma unroll
            for (int q = 0; q < 7; ++q) {
                float4 v = reinterpret_cast<const float4*>(rp)[q];
                pv[q*4+0] = v.x; pv[q*4+1] = v.y; pv[q*4+2] = v.z; pv[q*4+3] = v.w;
            }
            #pragma unroll
            for (int kx = 0; kx < 3; ++kx) {
                #pragma unroll
                for (int ic = 0; ic < 9; ++ic)
                    acc += pv[kx*9+ic] * cw[(ky*3+kx)*81 + ic*9 + oc];
            }
        }
        co_s[tid] = acc;
        conv_acc = acc;
    } else if (tid >= 128 && tid < 128 + NCH) {
        const int c = tid - 128;
        float s = 0.f;
        #pragma unroll
        for (int wv = 0; wv < 4; ++wv)
            #pragma unroll
            for (int i = 0; i < 24; ++i)
                s += colP[wv*ROWF + c + NCH*i];
        gap_s[c] = s * (1.0f / (float)NPIX);
    }
    __syncthreads();  // co_s, gap_s valid

    // ---- Phase C: wg1 clip+write; dense ----
    if (tid < 81) {
        const int oc = tid % 9;
        float n2 = 0.f;
        #pragma unroll
        for (int s = 0; s < 9; ++s) {
            float v = co_s[s*9 + oc];
            n2 += v*v;
        }
        float sc = 1.0f / fmaxf(sqrtf(n2), 1.0f);
        out[(size_t)j*81 + tid] = conv_acc * sc;

        float d = dense_b[tid];
        #pragma unroll
        for (int c = 0; c < NCH; ++c)
            d += gap_s[c] * dense_w[c*81 + tid];
        d_s[tid] = d;
    }
    __syncthreads();  // d_s valid

    // ---- Phase D: wg2 clip+write ----
    if (tid < 81) {
        const int bc = tid % 9;
        float n2 = 0.f;
        #pragma unroll
        for (int a = 0; a < 9; ++a) {
            float v = d_s[a*9 + bc];
            n2 += v*v;
        }
        float sc = 1.0f / fmaxf(sqrtf(n2), 1.0f);
        out[OUT2_OFF + (size_t)j*81 + tid] = d_s[tid] * sc;
    }
}

extern "C" void kernel_launch(void* const* d_in, const int* in_sizes, int n_in,
                              void* d_out, int out_size, void* d_ws, size_t ws_size,
                              hipStream_t stream) {
    const float* x       = (const float*)d_in[0];
    const float* conv_w  = (const float*)d_in[1];
    const float* conv_b  = (const float*)d_in[2];
    const float* dense_w = (const float*)d_in[3];
    const float* dense_b = (const float*)d_in[4];
    float* out = (float*)d_out;

    kgl_kernel<<<8192, 256, 0, stream>>>(x, conv_w, conv_b, dense_w, dense_b, out);
}

// Round 6
// 238.778 us; speedup vs baseline: 1.0261x; 1.0261x over previous
//
#include <hip/hip_runtime.h>

// KGL: per-patch kernel generation.  [R6 = revert to R4, the best variant]
//  x: (8, 768, 768, 9) fp32. PSZ=24 -> p1=p2=32, N=1024, N*B=8192 patches.
//  Patch flat index j = b*1024 + pi*32 + pj (raw-reshape preserves buffer order).
//  out[0 .. 663551]        = wg1: conv3x3 stride8 (pad=0 -> 3x3) clipped per-oc over spatial
//  out[663552 .. 1327103]  = wg2: (GAP @ dense_w + b) as 9x9, clipped per-column over rows
//
// Structure: NO patch LDS staging. GAP accumulates straight from global
// (coalesced 864B row loads, 12 independent float4 loads in flight per lane);
// conv reads its 729 floats from global (L1/L2/MSHR hits on the same lines the
// GAP stream fetches). LDS ~8KB -> 8 blocks/CU (wave-capped), 2 barriers.
// R5's tee-into-LDS variant regressed (+6us): it moved conv onto the LDS pipe
// and serialized it behind the streaming barrier. Keep conv on VMEM/L1.

#define PSZ 24
#define NCH 9
#define HW 768
#define NPIX (PSZ*PSZ)              // 576
#define ROWF (PSZ*NCH)              // 216 floats per patch row (54 float4, 16B-aligned)
#define ROWV4 54
#define XROWF (HW*NCH)              // 6912 floats per image row
#define OUT2_OFF 663552

__global__ __launch_bounds__(256) void kgl_kernel(
    const float* __restrict__ x,
    const float* __restrict__ conv_w,   // (3,3,9,9) HWIO flat, 729
    const float* __restrict__ conv_b,   // (9,)
    const float* __restrict__ dense_w,  // (9,81)
    const float* __restrict__ dense_b,  // (81,)
    float* __restrict__ out)
{
    __shared__ __align__(16) float cwA[732];   // wave0's copy (729 used)
    __shared__ __align__(16) float cwB[732];   // wave1's copy
    __shared__ __align__(16) float colA[ROWF]; // col sums rows 0..11  (wave2)
    __shared__ __align__(16) float colB[ROWF]; // col sums rows 12..23 (wave3)
    __shared__ float gapA[NCH];
    __shared__ float gapB[NCH];
    __shared__ float co_s[81];
    __shared__ float d_s[81];

    const int j   = blockIdx.x;
    const int b   = j >> 10;
    const int rem = j & 1023;
    const int pi  = rem >> 5;
    const int pj  = rem & 31;
    const int tid = threadIdx.x;

    const size_t base = ((size_t)(b*HW + pi*PSZ) * HW + (size_t)pj*PSZ) * NCH;
    const float* gbase = x + base;

    float conv_acc = 0.f;

    // ---- Phase A (no barrier inside) ----
    if (tid < 128) {
        // conv waves: wave-local conv_w copy (no barrier needed before use)
        float* cw = (tid < 64) ? cwA : cwB;
        const int lane = tid & 63;
        #pragma unroll
        for (int i = 0; i < 3; ++i) {
            int e = lane + i*64;
            if (e < 182)
                reinterpret_cast<float4*>(cw)[e] =
                    reinterpret_cast<const float4*>(conv_w)[e];
        }
        if (lane == 0) cw[728] = conv_w[728];

        if (tid < 81) {
            const int oy = tid / 27;
            const int ox = (tid / 9) % 3;
            const int oc = tid % 9;
            float acc = conv_b[oc];
            #pragma unroll
            for (int ky = 0; ky < 3; ++ky) {
                // 27 needed floats; load 7 aligned float4 (28), last elem ignored.
                const float* gp = gbase + (size_t)(oy*8+ky)*XROWF + (size_t)(ox*8)*NCH;
                const float4* gp4 = reinterpret_cast<const float4*>(gp);
                float pv[28];
                #pragma unroll
                for (int q = 0; q < 7; ++q) {
                    float4 v = gp4[q];
                    pv[q*4+0] = v.x; pv[q*4+1] = v.y; pv[q*4+2] = v.z; pv[q*4+3] = v.w;
                }
                #pragma unroll
                for (int kx = 0; kx < 3; ++kx) {
                    #pragma unroll
                    for (int ic = 0; ic < 9; ++ic)
                        acc += pv[kx*9+ic] * cw[(ky*3+kx)*81 + ic*9 + oc];
                }
            }
            co_s[tid] = acc;
            conv_acc = acc;
        }
    } else {
        // GAP waves: accumulate column sums straight from global.
        const int w  = (tid >= 192) ? 1 : 0;
        const int k  = tid & 63;
        const int r0 = w ? 12 : 0;
        if (k < ROWV4) {
            float4 acc = make_float4(0.f, 0.f, 0.f, 0.f);
            #pragma unroll
            for (int r = 0; r < 12; ++r) {
                float4 v = *reinterpret_cast<const float4*>(
                    gbase + (size_t)(r0 + r)*XROWF + (size_t)k*4);
                acc.x += v.x; acc.y += v.y; acc.z += v.z; acc.w += v.w;
            }
            reinterpret_cast<float4*>(w ? colB : colA)[k] = acc;
        }
        // wave-local fold 216 -> 9 channels
        if (k < NCH) {
            const float* col = w ? colB : colA;
            float s = 0.f;
            #pragma unroll
            for (int i = 0; i < 24; ++i) s += col[k + NCH*i];
            if (w) gapB[k] = s; else gapA[k] = s;
        }
    }
    __syncthreads();  // co_s, gapA, gapB valid

    // ---- Phase B: wg1 clip+write; dense ----
    if (tid < 81) {
        const int oc = tid % 9;
        float n2 = 0.f;
        #pragma unroll
        for (int s = 0; s < 9; ++s) {
            float v = co_s[s*9 + oc];
            n2 += v*v;
        }
        float sc = 1.0f / fmaxf(sqrtf(n2), 1.0f);
        out[(size_t)j*81 + tid] = conv_acc * sc;

        float d = dense_b[tid];
        #pragma unroll
        for (int c = 0; c < NCH; ++c)
            d += (gapA[c] + gapB[c]) * (1.0f/(float)NPIX) * dense_w[c*81 + tid];
        d_s[tid] = d;
    }
    __syncthreads();  // d_s valid

    // ---- Phase C: wg2 clip+write ----
    if (tid < 81) {
        const int bc = tid % 9;
        float n2 = 0.f;
        #pragma unroll
        for (int a = 0; a < 9; ++a) {
            float v = d_s[a*9 + bc];
            n2 += v*v;
        }
        float sc = 1.0f / fmaxf(sqrtf(n2), 1.0f);
        out[OUT2_OFF + (size_t)j*81 + tid] = d_s[tid] * sc;
    }
}

extern "C" void kernel_launch(void* const* d_in, const int* in_sizes, int n_in,
                              void* d_out, int out_size, void* d_ws, size_t ws_size,
                              hipStream_t stream) {
    const float* x       = (const float*)d_in[0];
    const float* conv_w  = (const float*)d_in[1];
    const float* conv_b  = (const float*)d_in[2];
    const float* dense_w = (const float*)d_in[3];
    const float* dense_b = (const float*)d_in[4];
    float* out = (float*)d_out;

    kgl_kernel<<<8192, 256, 0, stream>>>(x, conv_w, conv_b, dense_w, dense_b, out);
}